// Round 1
// 1550.049 us; speedup vs baseline: 1.2913x; 1.2913x over previous
//
#include <hip/hip_runtime.h>
#include <math.h>

#define N_    16
#define CIN_  256
#define DIM_  32
#define H_    128
#define W_    128
#define P_    (H_*W_)          // 16384
#define A_    192
#define R_    192
#define AR_   (A_*R_)          // 36864
#define CSR_CAP 18432          // per-angle pixlist capacity (16384 + 192*3 pad, rounded)
#define FSLOT 16520            // per-channel LDS floats: 128*129=16512 data + zero slot @16512
#define SENT  16512            // swizzled sentinel address (zero slot)

// ---------------- CSR build: per-angle pixel lists sorted by rho -----------
// One block per angle. rho computed in fp64 exactly like np.round (rint).
// Stored entries are PRE-SWIZZLED LDS addresses: a = p + (p>>7) (= y*129+x,
// max 16511, fits ushort). Segments padded to multiples of 4 with sentinel
// address 16512 (zero slot).
__global__ __launch_bounds__(256) void csr_build(
        unsigned short* __restrict__ pix, int* __restrict__ offg) {
    int a = blockIdx.x;
    __shared__ int cnt[192];
    __shared__ int off[193];
    __shared__ unsigned char rho_s[P_];       // 16 KB
    double theta = (double)a * (M_PI / 192.0);
    double irho  = 182.0 / 191.0;
    double ts = sin(theta) / irho;
    double tc = cos(theta) / irho;
    for (int i = threadIdx.x; i < 192; i += 256) cnt[i] = 0;
    __syncthreads();
    for (int p = threadIdx.x; p < P_; p += 256) {
        int y = p >> 7, x = p & 127;
        double v = __dadd_rn(__dmul_rn((double)(x - 64), tc),
                             __dmul_rn((double)(y - 64), ts));
        int r = (int)rint(v) + 96;
        r = r < 0 ? 0 : (r > 191 ? 191 : r);
        rho_s[p] = (unsigned char)r;
        atomicAdd(&cnt[r], 1);
    }
    __syncthreads();
    if (threadIdx.x == 0) {
        int run = 0;
        for (int r = 0; r < 192; ++r) { off[r] = run; run += (cnt[r] + 3) & ~3; }
        off[192] = run;
    }
    __syncthreads();
    if (threadIdx.x < 193) offg[a * 193 + threadIdx.x] = off[threadIdx.x];
    // reset cnt to running cursors
    for (int i = threadIdx.x; i < 192; i += 256) cnt[i] = off[i];
    __syncthreads();
    unsigned short* pa = pix + (size_t)a * CSR_CAP;
    for (int p = threadIdx.x; p < P_; p += 256) {
        int idx = atomicAdd(&cnt[rho_s[p]], 1);
        pa[idx] = (unsigned short)(p + (p >> 7));   // pre-swizzled address
    }
    __syncthreads();
    for (int r = threadIdx.x; r < 192; r += 256)
        for (int j = cnt[r]; j < off[r + 1]; ++j) pa[j] = SENT;  // sentinel
}

// ---------------- 1x1 conv + bias: x[16,256,128,128] -> pre[16,32,128,128] -
__global__ __launch_bounds__(256) void conv1x1_kernel(
        const float* __restrict__ x, const float* __restrict__ w,
        const float* __restrict__ b, float* __restrict__ out) {
    int g = blockIdx.x * 256 + threadIdx.x;   // 0..262143  (N*P)
    int n = g >> 14, p = g & (P_ - 1);
    const float* xp = x + (size_t)n * CIN_ * P_ + p;
    float acc[DIM_];
    #pragma unroll
    for (int co = 0; co < DIM_; ++co) acc[co] = b[co];
    for (int ci = 0; ci < CIN_; ++ci) {
        float v = xp[(size_t)ci * P_];
        #pragma unroll
        for (int co = 0; co < DIM_; ++co)
            acc[co] += v * w[co * CIN_ + ci];
    }
    float* op = out + (size_t)n * DIM_ * P_ + p;
    #pragma unroll
    for (int co = 0; co < DIM_; ++co) op[(size_t)co * P_] = acc[co];
}

// ---------------- per-channel sum / sumsq over [NC][S] slabs ---------------
__global__ __launch_bounds__(256) void stats_kernel(
        const float* __restrict__ in, int S,
        double* __restrict__ dsum, double* __restrict__ dsq) {
    int c = blockIdx.x & 31;
    const float* p = in + (size_t)blockIdx.x * S;
    double s = 0.0, q = 0.0;
    for (int i = threadIdx.x; i < S; i += 256) {
        double v = (double)p[i];
        s += v; q += v * v;
    }
    #pragma unroll
    for (int off = 32; off > 0; off >>= 1) {
        s += __shfl_down(s, off, 64);
        q += __shfl_down(q, off, 64);
    }
    __shared__ double ls[4], lq[4];
    int wv = threadIdx.x >> 6;
    if ((threadIdx.x & 63) == 0) { ls[wv] = s; lq[wv] = q; }
    __syncthreads();
    if (threadIdx.x == 0) {
        s = ls[0] + ls[1] + ls[2] + ls[3];
        q = lq[0] + lq[1] + lq[2] + lq[3];
        atomicAdd(&dsum[c], s);
        atomicAdd(&dsq[c], q);
    }
}

// ---------------- finalize BN: scale/shift per channel ---------------------
__global__ void fin_kernel(const double* __restrict__ dsum, const double* __restrict__ dsq,
                           const float* __restrict__ g, const float* __restrict__ be,
                           double cnt, float* __restrict__ scsh) {
    int c = threadIdx.x;
    if (c < 32) {
        double m = dsum[c] / cnt;
        double v = dsq[c] / cnt - m * m;
        double rstd = 1.0 / sqrt(v + 1e-5);
        double sc = (double)g[c] * rstd;
        scsh[c]      = (float)sc;
        scsh[32 + c] = (float)((double)be[c] - m * sc);
    }
}

// ---------------- DHT gather: feat(pre-BN) -> acc[n,c,192,192] -------------
// 256 blocks x 1024 threads (16 waves/CU, 1 block/CU due to 132 KB LDS).
// Each block stages 2 channels in LDS, INTERLEAVED as float2 {ch0,ch1} at
// swizzled address a = p + (p>>7) -> one ds_read_b64 fetches both channels.
// Linear segment map: seg = it*1024 + tid, 36 iters (36864 segments).
__global__ __launch_bounds__(1024) void dht_gather(
        const float* __restrict__ feat, const unsigned short* __restrict__ pix,
        const int* __restrict__ offg, const float* __restrict__ scsh,
        float* __restrict__ acc) {
    extern __shared__ float feat2[];          // 2 * FSLOT floats = 132160 B
    int nc0 = blockIdx.x * 2;
    {
        int c0 = nc0 & 31, c1 = (nc0 + 1) & 31;
        float sc0 = scsh[c0], sh0 = scsh[32 + c0];
        float sc1 = scsh[c1], sh1 = scsh[32 + c1];
        const float4* fp0 = (const float4*)(feat + (size_t)nc0 * P_);
        const float4* fp1 = (const float4*)(feat + (size_t)(nc0 + 1) * P_);
        float2* d = (float2*)feat2;
        for (int q = threadIdx.x; q < P_ / 4; q += 1024) {
            float4 f0 = fp0[q];
            float4 f1 = fp1[q];
            int p = q * 4;
            int base = p + (p >> 7);          // y*129 + x (x%4==0 -> contiguous)
            float2 v0, v1, v2, v3;
            v0.x = fmaxf(f0.x * sc0 + sh0, 0.f); v0.y = fmaxf(f1.x * sc1 + sh1, 0.f);
            v1.x = fmaxf(f0.y * sc0 + sh0, 0.f); v1.y = fmaxf(f1.y * sc1 + sh1, 0.f);
            v2.x = fmaxf(f0.z * sc0 + sh0, 0.f); v2.y = fmaxf(f1.z * sc1 + sh1, 0.f);
            v3.x = fmaxf(f0.w * sc0 + sh0, 0.f); v3.y = fmaxf(f1.w * sc1 + sh1, 0.f);
            d[base + 0] = v0;
            d[base + 1] = v1;
            d[base + 2] = v2;
            d[base + 3] = v3;
        }
        if (threadIdx.x < 16) feat2[2 * SENT + threadIdx.x] = 0.f;  // zero slot
    }
    __syncthreads();
    const float2* f2 = (const float2*)feat2;
    for (int it = 0; it < 36; ++it) {
        int seg = it * 1024 + threadIdx.x;    // 0..36863
        int a = seg / 192;
        int r = seg - a * 192;
        int o0 = offg[a * 193 + r];
        int o1 = offg[a * 193 + r + 1];
        const unsigned short* pl = pix + (size_t)a * CSR_CAP;
        float s0 = 0.f, s1 = 0.f;
        int j = o0;
        for (; j + 8 <= o1; j += 8) {
            ushort4 ua = *(const ushort4*)(pl + j);
            ushort4 ub = *(const ushort4*)(pl + j + 4);
            float2 v0 = f2[ua.x];
            float2 v1 = f2[ua.y];
            float2 v2 = f2[ua.z];
            float2 v3 = f2[ua.w];
            float2 v4 = f2[ub.x];
            float2 v5 = f2[ub.y];
            float2 v6 = f2[ub.z];
            float2 v7 = f2[ub.w];
            s0 += v0.x; s1 += v0.y;
            s0 += v1.x; s1 += v1.y;
            s0 += v2.x; s1 += v2.y;
            s0 += v3.x; s1 += v3.y;
            s0 += v4.x; s1 += v4.y;
            s0 += v5.x; s1 += v5.y;
            s0 += v6.x; s1 += v6.y;
            s0 += v7.x; s1 += v7.y;
        }
        if (j < o1) {                          // padded: remainder is exactly 4
            ushort4 ua = *(const ushort4*)(pl + j);
            float2 v0 = f2[ua.x];
            float2 v1 = f2[ua.y];
            float2 v2 = f2[ua.z];
            float2 v3 = f2[ua.w];
            s0 += v0.x; s1 += v0.y;
            s0 += v1.x; s1 += v1.y;
            s0 += v2.x; s1 += v2.y;
            s0 += v3.x; s1 += v3.y;
        }
        size_t ob = (size_t)nc0 * AR_ + seg;   // seg == a*R_ + r
        acc[ob] = s0;
        acc[ob + AR_] = s1;
    }
}

// ---------------- 3x3 conv (+optional input BN+ReLU) + bias ----------------
template <bool BN>
__global__ __launch_bounds__(256) void conv3x3_kernel(
        const float* __restrict__ in, const float* __restrict__ w,
        const float* __restrict__ b,
        const float* __restrict__ sc, const float* __restrict__ sh,
        float* __restrict__ out) {
    __shared__ float tile[18][20];
    int tx = threadIdx.x & 15, ty = threadIdx.x >> 4;
    int x0 = blockIdx.x * 16, y0 = blockIdx.y * 16, n = blockIdx.z;
    float acc[DIM_];
    #pragma unroll
    for (int co = 0; co < DIM_; ++co) acc[co] = b[co];

    for (int ci = 0; ci < DIM_; ++ci) {
        __syncthreads();
        const float* src = in + ((size_t)(n * DIM_ + ci)) * AR_;
        float csc = BN ? sc[ci] : 0.f, csh = BN ? sh[ci] : 0.f;
        for (int t = threadIdx.x; t < 18 * 18; t += 256) {
            int ly = t / 18, lx = t - ly * 18;
            int gy = y0 - 1 + ly, gx = x0 - 1 + lx;
            float v = 0.f;
            if (gy >= 0 && gy < 192 && gx >= 0 && gx < 192) {
                v = src[gy * 192 + gx];
                if (BN) v = fmaxf(v * csc + csh, 0.f);
            }
            tile[ly][lx] = v;
        }
        __syncthreads();
        float v[9];
        #pragma unroll
        for (int k = 0; k < 9; ++k) v[k] = tile[ty + k / 3][tx + k % 3];
        const float* wp = w + ci * 9;          // w[co][ci][k]: co stride 288
        #pragma unroll
        for (int co = 0; co < DIM_; ++co) {
            #pragma unroll
            for (int k = 0; k < 9; ++k)
                acc[co] += v[k] * wp[co * 288 + k];
        }
    }
    size_t o = ((size_t)(n * DIM_) * 192 + (y0 + ty)) * 192 + x0 + tx;
    #pragma unroll
    for (int co = 0; co < DIM_; ++co) out[o + (size_t)co * AR_] = acc[co];
}

// ---------------- final BN + ReLU -> d_out ---------------------------------
__global__ __launch_bounds__(256) void bnrelu_kernel(
        const float* __restrict__ in, const float* __restrict__ scsh,
        float* __restrict__ out) {
    int i = blockIdx.x * 256 + threadIdx.x;   // float4 index, total 4718592
    if (i >= 4718592) return;
    int c = (i / 9216) & 31;                  // 9216 float4 per channel slab
    float sc = scsh[c], sh = scsh[32 + c];
    float4 v = ((const float4*)in)[i];
    v.x = fmaxf(v.x * sc + sh, 0.f);
    v.y = fmaxf(v.y * sc + sh, 0.f);
    v.z = fmaxf(v.z * sc + sh, 0.f);
    v.w = fmaxf(v.w * sc + sh, 0.f);
    ((float4*)out)[i] = v;
}

extern "C" void kernel_launch(void* const* d_in, const int* in_sizes, int n_in,
                              void* d_out, int out_size, void* d_ws, size_t ws_size,
                              hipStream_t stream) {
    const float* x   = (const float*)d_in[0];
    const float* w1  = (const float*)d_in[1];
    const float* b1  = (const float*)d_in[2];
    const float* g1  = (const float*)d_in[3];
    const float* be1 = (const float*)d_in[4];
    const float* w2  = (const float*)d_in[5];
    const float* b2  = (const float*)d_in[6];
    const float* g2  = (const float*)d_in[7];
    const float* be2 = (const float*)d_in[8];
    const float* w3  = (const float*)d_in[9];
    const float* b3  = (const float*)d_in[10];
    const float* g3  = (const float*)d_in[11];
    const float* be3 = (const float*)d_in[12];
    float* out = (float*)d_out;

    char* ws = (char*)d_ws;
    float* bufA = (float*)(ws);                       // [0, 75497472)
    //   conv1 out uses [0, 33554432); CSR lives in the tail (dead once conv2 runs)
    unsigned short* pix = (unsigned short*)(ws + 33554432);   // 7,077,888 B
    int*   offg  = (int*)(ws + 40632320);                     // 148,224 B
    float* bufB  = (float*)(ws + 75497472);                   // 75,497,472 B
    double* stats = (double*)(ws + 150994944);                // 1536 B
    float*  scsh  = (float*)(ws + 150996480);                 // 768 B

    hipMemsetAsync(stats, 0, 192 * sizeof(double), stream);
    csr_build<<<192, 256, 0, stream>>>(pix, offg);

    // stage 1: 1x1 conv -> bufA (pre-BN), stats, finalize
    conv1x1_kernel<<<1024, 256, 0, stream>>>(x, w1, b1, bufA);
    stats_kernel<<<512, 256, 0, stream>>>(bufA, P_, stats + 0, stats + 32);
    fin_kernel<<<1, 64, 0, stream>>>(stats + 0, stats + 32, g1, be1,
                                     (double)(N_ * P_), scsh);

    // stage 2: DHT gather (BN1+ReLU applied while staging to LDS) -> bufB
    hipFuncSetAttribute((const void*)dht_gather,
                        hipFuncAttributeMaxDynamicSharedMemorySize,
                        2 * FSLOT * sizeof(float));
    dht_gather<<<256, 1024, 2 * FSLOT * sizeof(float), stream>>>(
        bufA, pix, offg, scsh, bufB);

    // stage 3: conv2 (raw input) -> bufA, stats, finalize
    conv3x3_kernel<false><<<dim3(12, 12, 16), 256, 0, stream>>>(
        bufB, w2, b2, nullptr, nullptr, bufA);
    stats_kernel<<<512, 256, 0, stream>>>(bufA, AR_, stats + 64, stats + 96);
    fin_kernel<<<1, 64, 0, stream>>>(stats + 64, stats + 96, g2, be2,
                                     (double)(N_ * AR_), scsh + 64);

    // stage 4: conv3 (BN2+ReLU on the fly) -> bufB, stats, finalize
    conv3x3_kernel<true><<<dim3(12, 12, 16), 256, 0, stream>>>(
        bufA, w3, b3, scsh + 64, scsh + 96, bufB);
    stats_kernel<<<512, 256, 0, stream>>>(bufB, AR_, stats + 128, stats + 160);
    fin_kernel<<<1, 64, 0, stream>>>(stats + 128, stats + 160, g3, be3,
                                     (double)(N_ * AR_), scsh + 128);

    // epilogue: BN3 + ReLU -> out
    bnrelu_kernel<<<18432, 256, 0, stream>>>(bufB, scsh + 128, out);
}

// Round 2
// 1350.702 us; speedup vs baseline: 1.4818x; 1.1476x over previous
//
#include <hip/hip_runtime.h>
#include <hip/hip_fp16.h>
#include <math.h>

#define N_    16
#define CIN_  256
#define DIM_  32
#define H_    128
#define W_    128
#define P_    (H_*W_)          // 16384
#define A_    192
#define R_    192
#define AR_   (A_*R_)          // 36864
#define CSR_CAP 18432          // per-angle pixlist capacity (16384 + 192*3 pad, rounded)
#define NWORD 16520            // LDS 8-byte words: 128*129=16512 data + sentinel @16512
#define SENT  16512            // swizzled sentinel word (zero slot)

// 4 fp16 channels per pixel, one ds_read_b64
struct alignas(8) h4 { __half2 a, b; };

// swizzled word index for pixel p: y*129 + (x ^ ((y&7)<<2))
// - keeps 4-aligned x-groups contiguous (XOR only touches bits 2..4)
// - mixes y nonlinearly into the bank index to break diagonal-line degeneracy
__device__ __forceinline__ int swz(int p) {
    int y = p >> 7, x = p & 127;
    return y * 129 + (x ^ ((y & 7) << 2));
}

// ---------------- CSR build: per-angle pixel lists sorted by rho -----------
// One block per angle. rho computed in fp64 exactly like np.round (rint).
// Stored entries are PRE-SWIZZLED LDS word indices (max 16510, fits ushort).
// Segments padded to multiples of 4 with sentinel word 16512 (zero slot).
__global__ __launch_bounds__(256) void csr_build(
        unsigned short* __restrict__ pix, int* __restrict__ offg) {
    int a = blockIdx.x;
    __shared__ int cnt[192];
    __shared__ int off[193];
    __shared__ unsigned char rho_s[P_];       // 16 KB
    double theta = (double)a * (M_PI / 192.0);
    double irho  = 182.0 / 191.0;
    double ts = sin(theta) / irho;
    double tc = cos(theta) / irho;
    for (int i = threadIdx.x; i < 192; i += 256) cnt[i] = 0;
    __syncthreads();
    for (int p = threadIdx.x; p < P_; p += 256) {
        int y = p >> 7, x = p & 127;
        double v = __dadd_rn(__dmul_rn((double)(x - 64), tc),
                             __dmul_rn((double)(y - 64), ts));
        int r = (int)rint(v) + 96;
        r = r < 0 ? 0 : (r > 191 ? 191 : r);
        rho_s[p] = (unsigned char)r;
        atomicAdd(&cnt[r], 1);
    }
    __syncthreads();
    if (threadIdx.x == 0) {
        int run = 0;
        for (int r = 0; r < 192; ++r) { off[r] = run; run += (cnt[r] + 3) & ~3; }
        off[192] = run;
    }
    __syncthreads();
    if (threadIdx.x < 193) offg[a * 193 + threadIdx.x] = off[threadIdx.x];
    // reset cnt to running cursors
    for (int i = threadIdx.x; i < 192; i += 256) cnt[i] = off[i];
    __syncthreads();
    unsigned short* pa = pix + (size_t)a * CSR_CAP;
    for (int p = threadIdx.x; p < P_; p += 256) {
        int idx = atomicAdd(&cnt[rho_s[p]], 1);
        pa[idx] = (unsigned short)swz(p);     // pre-swizzled word index
    }
    __syncthreads();
    for (int r = threadIdx.x; r < 192; r += 256)
        for (int j = cnt[r]; j < off[r + 1]; ++j) pa[j] = SENT;  // sentinel
}

// ---------------- 1x1 conv + bias: x[16,256,128,128] -> pre[16,32,128,128] -
__global__ __launch_bounds__(256) void conv1x1_kernel(
        const float* __restrict__ x, const float* __restrict__ w,
        const float* __restrict__ b, float* __restrict__ out) {
    int g = blockIdx.x * 256 + threadIdx.x;   // 0..262143  (N*P)
    int n = g >> 14, p = g & (P_ - 1);
    const float* xp = x + (size_t)n * CIN_ * P_ + p;
    float acc[DIM_];
    #pragma unroll
    for (int co = 0; co < DIM_; ++co) acc[co] = b[co];
    for (int ci = 0; ci < CIN_; ++ci) {
        float v = xp[(size_t)ci * P_];
        #pragma unroll
        for (int co = 0; co < DIM_; ++co)
            acc[co] += v * w[co * CIN_ + ci];
    }
    float* op = out + (size_t)n * DIM_ * P_ + p;
    #pragma unroll
    for (int co = 0; co < DIM_; ++co) op[(size_t)co * P_] = acc[co];
}

// ---------------- per-channel sum / sumsq over [NC][S] slabs ---------------
__global__ __launch_bounds__(256) void stats_kernel(
        const float* __restrict__ in, int S,
        double* __restrict__ dsum, double* __restrict__ dsq) {
    int c = blockIdx.x & 31;
    const float* p = in + (size_t)blockIdx.x * S;
    double s = 0.0, q = 0.0;
    for (int i = threadIdx.x; i < S; i += 256) {
        double v = (double)p[i];
        s += v; q += v * v;
    }
    #pragma unroll
    for (int off = 32; off > 0; off >>= 1) {
        s += __shfl_down(s, off, 64);
        q += __shfl_down(q, off, 64);
    }
    __shared__ double ls[4], lq[4];
    int wv = threadIdx.x >> 6;
    if ((threadIdx.x & 63) == 0) { ls[wv] = s; lq[wv] = q; }
    __syncthreads();
    if (threadIdx.x == 0) {
        s = ls[0] + ls[1] + ls[2] + ls[3];
        q = lq[0] + lq[1] + lq[2] + lq[3];
        atomicAdd(&dsum[c], s);
        atomicAdd(&dsq[c], q);
    }
}

// ---------------- finalize BN: scale/shift per channel ---------------------
__global__ void fin_kernel(const double* __restrict__ dsum, const double* __restrict__ dsq,
                           const float* __restrict__ g, const float* __restrict__ be,
                           double cnt, float* __restrict__ scsh) {
    int c = threadIdx.x;
    if (c < 32) {
        double m = dsum[c] / cnt;
        double v = dsq[c] / cnt - m * m;
        double rstd = 1.0 / sqrt(v + 1e-5);
        double sc = (double)g[c] * rstd;
        scsh[c]      = (float)sc;
        scsh[32 + c] = (float)((double)be[c] - m * sc);
    }
}

// ---------------- DHT gather: feat(pre-BN) -> acc[n,c,192,192] -------------
// 256 blocks x 1024 threads. Block = (channel-quad, angle-half).
// Stages 4 channels as fp16 packed per pixel (8 B) at XOR-swizzled word
// addresses -> ONE ds_read_b64 per pixel serves 4 channels. Unpack+accumulate
// via (float)h * one + acc with runtime one==1.0f -> v_fma_mix_f32.
__global__ __launch_bounds__(1024) void dht_gather(
        const float* __restrict__ feat, const unsigned short* __restrict__ pix,
        const int* __restrict__ offg, const float* __restrict__ scsh,
        float one, float* __restrict__ acc) {
    extern __shared__ h4 d[];                 // NWORD * 8 B = 132160 B
    int quad = blockIdx.x >> 1, ah = blockIdx.x & 1;
    int nc0 = quad * 4;
    {
        int cb = nc0 & 31;                    // channels cb..cb+3
        float s0 = scsh[cb],     h0 = scsh[32 + cb];
        float s1 = scsh[cb + 1], h1 = scsh[33 + cb];
        float s2 = scsh[cb + 2], h2 = scsh[34 + cb];
        float s3 = scsh[cb + 3], h3 = scsh[35 + cb];
        const float4* f0p = (const float4*)(feat + (size_t)(nc0 + 0) * P_);
        const float4* f1p = (const float4*)(feat + (size_t)(nc0 + 1) * P_);
        const float4* f2p = (const float4*)(feat + (size_t)(nc0 + 2) * P_);
        const float4* f3p = (const float4*)(feat + (size_t)(nc0 + 3) * P_);
        for (int q = threadIdx.x; q < P_ / 4; q += 1024) {
            float4 a0 = f0p[q], a1 = f1p[q], a2 = f2p[q], a3 = f3p[q];
            int p = q * 4;
            int base = swz(p);                // 4-group stays contiguous
            h4 w;
            w.a = __halves2half2(__float2half(fmaxf(a0.x * s0 + h0, 0.f)),
                                 __float2half(fmaxf(a1.x * s1 + h1, 0.f)));
            w.b = __halves2half2(__float2half(fmaxf(a2.x * s2 + h2, 0.f)),
                                 __float2half(fmaxf(a3.x * s3 + h3, 0.f)));
            d[base + 0] = w;
            w.a = __halves2half2(__float2half(fmaxf(a0.y * s0 + h0, 0.f)),
                                 __float2half(fmaxf(a1.y * s1 + h1, 0.f)));
            w.b = __halves2half2(__float2half(fmaxf(a2.y * s2 + h2, 0.f)),
                                 __float2half(fmaxf(a3.y * s3 + h3, 0.f)));
            d[base + 1] = w;
            w.a = __halves2half2(__float2half(fmaxf(a0.z * s0 + h0, 0.f)),
                                 __float2half(fmaxf(a1.z * s1 + h1, 0.f)));
            w.b = __halves2half2(__float2half(fmaxf(a2.z * s2 + h2, 0.f)),
                                 __float2half(fmaxf(a3.z * s3 + h3, 0.f)));
            d[base + 2] = w;
            w.a = __halves2half2(__float2half(fmaxf(a0.w * s0 + h0, 0.f)),
                                 __float2half(fmaxf(a1.w * s1 + h1, 0.f)));
            w.b = __halves2half2(__float2half(fmaxf(a2.w * s2 + h2, 0.f)),
                                 __float2half(fmaxf(a3.w * s3 + h3, 0.f)));
            d[base + 3] = w;
        }
        if (threadIdx.x < 8) {                // zero sentinel words
            *(uint2*)&d[SENT + threadIdx.x] = make_uint2(0u, 0u);
        }
    }
    __syncthreads();
    int abase = ah * 96;
    for (int it = 0; it < 18; ++it) {
        int seg = it * 1024 + threadIdx.x;    // 0..18431 (96 angles x 192 rho)
        int al = seg / 192, r = seg - al * 192;
        int a = abase + al;
        int o0 = offg[a * 193 + r];
        int o1 = offg[a * 193 + r + 1];
        const unsigned short* pl = pix + (size_t)a * CSR_CAP;
        float s0 = 0.f, s1 = 0.f, s2 = 0.f, s3 = 0.f;
        int j = o0;
        for (; j + 8 <= o1; j += 8) {
            ushort4 ua = *(const ushort4*)(pl + j);
            ushort4 ub = *(const ushort4*)(pl + j + 4);
            h4 v0 = d[ua.x];
            h4 v1 = d[ua.y];
            h4 v2 = d[ua.z];
            h4 v3 = d[ua.w];
            h4 v4 = d[ub.x];
            h4 v5 = d[ub.y];
            h4 v6 = d[ub.z];
            h4 v7 = d[ub.w];
            s0 += __low2float(v0.a) * one; s1 += __high2float(v0.a) * one;
            s2 += __low2float(v0.b) * one; s3 += __high2float(v0.b) * one;
            s0 += __low2float(v1.a) * one; s1 += __high2float(v1.a) * one;
            s2 += __low2float(v1.b) * one; s3 += __high2float(v1.b) * one;
            s0 += __low2float(v2.a) * one; s1 += __high2float(v2.a) * one;
            s2 += __low2float(v2.b) * one; s3 += __high2float(v2.b) * one;
            s0 += __low2float(v3.a) * one; s1 += __high2float(v3.a) * one;
            s2 += __low2float(v3.b) * one; s3 += __high2float(v3.b) * one;
            s0 += __low2float(v4.a) * one; s1 += __high2float(v4.a) * one;
            s2 += __low2float(v4.b) * one; s3 += __high2float(v4.b) * one;
            s0 += __low2float(v5.a) * one; s1 += __high2float(v5.a) * one;
            s2 += __low2float(v5.b) * one; s3 += __high2float(v5.b) * one;
            s0 += __low2float(v6.a) * one; s1 += __high2float(v6.a) * one;
            s2 += __low2float(v6.b) * one; s3 += __high2float(v6.b) * one;
            s0 += __low2float(v7.a) * one; s1 += __high2float(v7.a) * one;
            s2 += __low2float(v7.b) * one; s3 += __high2float(v7.b) * one;
        }
        if (j < o1) {                          // padded: remainder is exactly 4
            ushort4 ua = *(const ushort4*)(pl + j);
            h4 v0 = d[ua.x];
            h4 v1 = d[ua.y];
            h4 v2 = d[ua.z];
            h4 v3 = d[ua.w];
            s0 += __low2float(v0.a) * one; s1 += __high2float(v0.a) * one;
            s2 += __low2float(v0.b) * one; s3 += __high2float(v0.b) * one;
            s0 += __low2float(v1.a) * one; s1 += __high2float(v1.a) * one;
            s2 += __low2float(v1.b) * one; s3 += __high2float(v1.b) * one;
            s0 += __low2float(v2.a) * one; s1 += __high2float(v2.a) * one;
            s2 += __low2float(v2.b) * one; s3 += __high2float(v2.b) * one;
            s0 += __low2float(v3.a) * one; s1 += __high2float(v3.a) * one;
            s2 += __low2float(v3.b) * one; s3 += __high2float(v3.b) * one;
        }
        size_t ob = (size_t)nc0 * AR_ + (size_t)a * R_ + r;
        acc[ob]           = s0;
        acc[ob + AR_]     = s1;
        acc[ob + 2 * AR_] = s2;
        acc[ob + 3 * AR_] = s3;
    }
}

// ---------------- 3x3 conv (+optional input BN+ReLU) + bias ----------------
template <bool BN>
__global__ __launch_bounds__(256) void conv3x3_kernel(
        const float* __restrict__ in, const float* __restrict__ w,
        const float* __restrict__ b,
        const float* __restrict__ sc, const float* __restrict__ sh,
        float* __restrict__ out) {
    __shared__ float tile[18][20];
    int tx = threadIdx.x & 15, ty = threadIdx.x >> 4;
    int x0 = blockIdx.x * 16, y0 = blockIdx.y * 16, n = blockIdx.z;
    float acc[DIM_];
    #pragma unroll
    for (int co = 0; co < DIM_; ++co) acc[co] = b[co];

    for (int ci = 0; ci < DIM_; ++ci) {
        __syncthreads();
        const float* src = in + ((size_t)(n * DIM_ + ci)) * AR_;
        float csc = BN ? sc[ci] : 0.f, csh = BN ? sh[ci] : 0.f;
        for (int t = threadIdx.x; t < 18 * 18; t += 256) {
            int ly = t / 18, lx = t - ly * 18;
            int gy = y0 - 1 + ly, gx = x0 - 1 + lx;
            float v = 0.f;
            if (gy >= 0 && gy < 192 && gx >= 0 && gx < 192) {
                v = src[gy * 192 + gx];
                if (BN) v = fmaxf(v * csc + csh, 0.f);
            }
            tile[ly][lx] = v;
        }
        __syncthreads();
        float v[9];
        #pragma unroll
        for (int k = 0; k < 9; ++k) v[k] = tile[ty + k / 3][tx + k % 3];
        const float* wp = w + ci * 9;          // w[co][ci][k]: co stride 288
        #pragma unroll
        for (int co = 0; co < DIM_; ++co) {
            #pragma unroll
            for (int k = 0; k < 9; ++k)
                acc[co] += v[k] * wp[co * 288 + k];
        }
    }
    size_t o = ((size_t)(n * DIM_) * 192 + (y0 + ty)) * 192 + x0 + tx;
    #pragma unroll
    for (int co = 0; co < DIM_; ++co) out[o + (size_t)co * AR_] = acc[co];
}

// ---------------- final BN + ReLU -> d_out ---------------------------------
__global__ __launch_bounds__(256) void bnrelu_kernel(
        const float* __restrict__ in, const float* __restrict__ scsh,
        float* __restrict__ out) {
    int i = blockIdx.x * 256 + threadIdx.x;   // float4 index, total 4718592
    if (i >= 4718592) return;
    int c = (i / 9216) & 31;                  // 9216 float4 per channel slab
    float sc = scsh[c], sh = scsh[32 + c];
    float4 v = ((const float4*)in)[i];
    v.x = fmaxf(v.x * sc + sh, 0.f);
    v.y = fmaxf(v.y * sc + sh, 0.f);
    v.z = fmaxf(v.z * sc + sh, 0.f);
    v.w = fmaxf(v.w * sc + sh, 0.f);
    ((float4*)out)[i] = v;
}

extern "C" void kernel_launch(void* const* d_in, const int* in_sizes, int n_in,
                              void* d_out, int out_size, void* d_ws, size_t ws_size,
                              hipStream_t stream) {
    const float* x   = (const float*)d_in[0];
    const float* w1  = (const float*)d_in[1];
    const float* b1  = (const float*)d_in[2];
    const float* g1  = (const float*)d_in[3];
    const float* be1 = (const float*)d_in[4];
    const float* w2  = (const float*)d_in[5];
    const float* b2  = (const float*)d_in[6];
    const float* g2  = (const float*)d_in[7];
    const float* be2 = (const float*)d_in[8];
    const float* w3  = (const float*)d_in[9];
    const float* b3  = (const float*)d_in[10];
    const float* g3  = (const float*)d_in[11];
    const float* be3 = (const float*)d_in[12];
    float* out = (float*)d_out;

    char* ws = (char*)d_ws;
    float* bufA = (float*)(ws);                       // [0, 75497472)
    //   conv1 out uses [0, 33554432); CSR lives in the tail (dead once conv2 runs)
    unsigned short* pix = (unsigned short*)(ws + 33554432);   // 7,077,888 B
    int*   offg  = (int*)(ws + 40632320);                     // 148,224 B
    float* bufB  = (float*)(ws + 75497472);                   // 75,497,472 B
    double* stats = (double*)(ws + 150994944);                // 1536 B
    float*  scsh  = (float*)(ws + 150996480);                 // 768 B

    hipMemsetAsync(stats, 0, 192 * sizeof(double), stream);
    csr_build<<<192, 256, 0, stream>>>(pix, offg);

    // stage 1: 1x1 conv -> bufA (pre-BN), stats, finalize
    conv1x1_kernel<<<1024, 256, 0, stream>>>(x, w1, b1, bufA);
    stats_kernel<<<512, 256, 0, stream>>>(bufA, P_, stats + 0, stats + 32);
    fin_kernel<<<1, 64, 0, stream>>>(stats + 0, stats + 32, g1, be1,
                                     (double)(N_ * P_), scsh);

    // stage 2: DHT gather (BN1+ReLU+fp16 pack while staging to LDS) -> bufB
    hipFuncSetAttribute((const void*)dht_gather,
                        hipFuncAttributeMaxDynamicSharedMemorySize,
                        NWORD * sizeof(h4));
    dht_gather<<<256, 1024, NWORD * sizeof(h4), stream>>>(
        bufA, pix, offg, scsh, 1.0f, bufB);

    // stage 3: conv2 (raw input) -> bufA, stats, finalize
    conv3x3_kernel<false><<<dim3(12, 12, 16), 256, 0, stream>>>(
        bufB, w2, b2, nullptr, nullptr, bufA);
    stats_kernel<<<512, 256, 0, stream>>>(bufA, AR_, stats + 64, stats + 96);
    fin_kernel<<<1, 64, 0, stream>>>(stats + 64, stats + 96, g2, be2,
                                     (double)(N_ * AR_), scsh + 64);

    // stage 4: conv3 (BN2+ReLU on the fly) -> bufB, stats, finalize
    conv3x3_kernel<true><<<dim3(12, 12, 16), 256, 0, stream>>>(
        bufA, w3, b3, scsh + 64, scsh + 96, bufB);
    stats_kernel<<<512, 256, 0, stream>>>(bufB, AR_, stats + 128, stats + 160);
    fin_kernel<<<1, 64, 0, stream>>>(stats + 128, stats + 160, g3, be3,
                                     (double)(N_ * AR_), scsh + 128);

    // epilogue: BN3 + ReLU -> out
    bnrelu_kernel<<<18432, 256, 0, stream>>>(bufB, scsh + 128, out);
}